// Round 5
// baseline (981.157 us; speedup 1.0000x reference)
//
#include <hip/hip_runtime.h>
#include <hip/hip_cooperative_groups.h>

namespace cg = cooperative_groups;

// Problem constants (fixed instance): all float tensors are float32 on device.
#define NPL   16384        // nodes per level
#define DIM   64
#define CPN   8            // children per node
#define EPL   (NPL * CPN)  // edges per level block = 131072
#define NLEV  8

#define TPB   512
#define WPB   (TPB / 64)   // 8 waves per block

// Cooperative config: 256 blocks = 1 block/CU (proved co-resident in R4).
#define CBLOCKS 256
#define C_NPW   ((NPL / CBLOCKS) / WPB)   // 8 nodes per wave per level

// Fallback (per-level normal launches) config.
#define FBLOCKS 1024
#define F_NPW   ((NPL / FBLOCKS) / WPB)   // 2 nodes per wave per level

__device__ __forceinline__ void load_wrow(float* dst, const float* W, int row) {
    const float4* p = (const float4*)(W + row * DIM);   // 256B-aligned row
    #pragma unroll
    for (int q = 0; q < DIM / 4; ++q) {
        float4 v = p[q];
        dst[4*q+0] = v.x; dst[4*q+1] = v.y;
        dst[4*q+2] = v.z; dst[4*q+3] = v.w;
    }
}

// Process `nnodes` consecutive nodes of level `lvl` on one wave.
// Wave = node (sequential); lane = output dim.
// Software pipeline: gathers for node c+1 are ISSUED (not summed!) before
// node c's GEMV, so their latency hides under ~640 cyc of compute. The sum
// (and thus the vmcnt wait) happens one iteration later.
__device__ __forceinline__ void run_level(
    const float* __restrict__ x, const int* __restrict__ eb,  // eb = src+(lvl-1)*EPL
    float* __restrict__ out,
    const float* wr, const float* wl, float bias,
    int lvl, int lane, int w, int pbase, int nnodes,
    float (*sX)[DIM], float (*sA)[DIM])
{
    const long gbase = (long)lvl * NPL;

    float xc, xn;
    float gc[CPN], gn[CPN];

    // Preload node 0.
    xc = x[(gbase + pbase) * DIM + lane];
    if (lvl > 0) {
        const int* ep = eb + (long)pbase * CPN;
        #pragma unroll
        for (int j = 0; j < CPN; ++j)
            gc[j] = out[(long)ep[j] * DIM + lane];     // coalesced 256B/wave
    }

    for (int c = 0; c < nnodes; ++c) {
        // Issue (don't consume) node c+1's loads.
        if (c + 1 < nnodes) {
            const int p1 = pbase + c + 1;
            xn = x[(gbase + p1) * DIM + lane];
            if (lvl > 0) {
                const int* ep = eb + (long)p1 * CPN;
                #pragma unroll
                for (int j = 0; j < CPN; ++j)
                    gn[j] = out[(long)ep[j] * DIM + lane];
            }
        }

        // Consume node c (loads issued >= 1 iteration ago).
        float agg = 0.0f;
        if (lvl > 0) {
            #pragma unroll
            for (int j = 0; j < CPN; ++j) agg += gc[j];
        }
        // Per-wave LDS broadcast slot; DS pipe is in-order within a wave,
        // so no barrier needed between iterations.
        sX[w][lane] = xc;
        sA[w][lane] = agg;

        // Dual GEMV, 4 interleaved accumulators (issue-bound, not latency).
        float a0 = 0.f, a1 = 0.f, a2 = 0.f, a3 = (lvl > 0) ? bias : 0.f;
        const float4* A = (const float4*)sX[w];   // broadcast reads: conflict-free
        const float4* B = (const float4*)sA[w];
        #pragma unroll
        for (int k = 0; k < DIM / 4; ++k) {
            float4 av = A[k], bv = B[k];
            a0 += av.x * wr[4*k+0];
            a1 += av.y * wr[4*k+1];
            a2 += av.z * wr[4*k+2];
            a3 += av.w * wr[4*k+3];
            a0 += bv.x * wl[4*k+0];
            a1 += bv.y * wl[4*k+1];
            a2 += bv.z * wl[4*k+2];
            a3 += bv.w * wl[4*k+3];
        }
        float r = (a0 + a1) + (a2 + a3);
        if (lvl > 0) r = tanhf(r);
        out[(gbase + pbase + c) * DIM + lane] = r;

        // Rotate pipeline registers.
        xc = xn;
        #pragma unroll
        for (int j = 0; j < CPN; ++j) gc[j] = gn[j];
    }
}

// ---------------- Fused cooperative kernel (1 dispatch) ----------------
__global__ __launch_bounds__(TPB, 2) void dag_fused(
    const float* __restrict__ x, const int* __restrict__ src,
    const float* __restrict__ Wl, const float* __restrict__ bl,
    const float* __restrict__ Wr, float* __restrict__ out)
{
    __shared__ __align__(16) float sX[WPB][DIM];
    __shared__ __align__(16) float sA[WPB][DIM];

    const int lane = threadIdx.x & 63;
    const int w    = threadIdx.x >> 6;

    cg::grid_group grid = cg::this_grid();

    // Weights for this lane's output dim, held in VGPRs across all levels.
    float wr[DIM], wl[DIM];
    load_wrow(wr, Wr, lane);
    load_wrow(wl, Wl, lane);
    const float bias = bl[lane];

    const int pbase = blockIdx.x * (NPL / CBLOCKS) + w * C_NPW;

    for (int lvl = 0; lvl < NLEV; ++lvl) {
        run_level(x, src + (long)(lvl - 1) * EPL, out,
                  wr, wl, bias, lvl, lane, w, pbase, C_NPW, sX, sA);
        // Level writes must be visible across XCDs before next level's
        // gathers (per-XCD L2 non-coherent): release, grid barrier, acquire.
        __threadfence();
        grid.sync();
        __threadfence();
    }
}

// ---------------- Fallback: one normal kernel per level ----------------
__global__ __launch_bounds__(TPB) void dag_level(
    const float* __restrict__ x, const int* __restrict__ src,
    const float* __restrict__ Wl, const float* __restrict__ bl,
    const float* __restrict__ Wr, float* __restrict__ out, int lvl)
{
    __shared__ __align__(16) float sX[WPB][DIM];
    __shared__ __align__(16) float sA[WPB][DIM];

    const int lane = threadIdx.x & 63;
    const int w    = threadIdx.x >> 6;

    float wr[DIM], wl[DIM];
    load_wrow(wr, Wr, lane);
    load_wrow(wl, Wl, lane);
    const float bias = bl[lane];

    const int pbase = blockIdx.x * (NPL / FBLOCKS) + w * F_NPW;
    run_level(x, src + (long)(lvl - 1) * EPL, out,
              wr, wl, bias, lvl, lane, w, pbase, F_NPW, sX, sA);
}

extern "C" void kernel_launch(void* const* d_in, const int* in_sizes, int n_in,
                              void* d_out, int out_size, void* d_ws, size_t ws_size,
                              hipStream_t stream) {
    const float* x  = (const float*)d_in[0];   // [131072,64] f32
    const int*   ei = (const int*)d_in[1];     // [2, 917504] int32
    const float* Wl = (const float*)d_in[2];   // [64,64] f32
    const float* bl = (const float*)d_in[3];   // [64]    f32
    const float* Wr = (const float*)d_in[4];   // [64,64] f32
    float* out = (float*)d_out;                // [131072,64] f32

    const int* src = ei;                       // first E entries = src row

    void* args[] = {(void*)&x, (void*)&src, (void*)&Wl, (void*)&bl,
                    (void*)&Wr, (void*)&out};
    hipError_t e = hipLaunchCooperativeKernel((const void*)dag_fused,
                                              dim3(CBLOCKS), dim3(TPB),
                                              args, 0, stream);
    if (e != hipSuccess) {
        (void)hipGetLastError();               // clear sticky error
        // Proven-correct fallback: 8 dependent per-level launches.
        for (int lvl = 0; lvl < NLEV; ++lvl) {
            hipLaunchKernelGGL(dag_level, dim3(FBLOCKS), dim3(TPB), 0, stream,
                               x, src, Wl, bl, Wr, out, lvl);
        }
    }
}

// Round 6
// 267.616 us; speedup vs baseline: 3.6663x; 3.6663x over previous
//
#include <hip/hip_runtime.h>

// Problem constants (fixed instance): all float tensors are float32 on device.
#define NPL   16384        // nodes per level
#define DIM   64
#define CPN   8            // children per node
#define EPL   (NPL * CPN)  // edges per level block = 131072
#define NLEV  8

#define TPB   512
#define WPB   (TPB / 64)   // 8 waves per block

// Cooperative config: 256 blocks x 512 thr = 1 block/CU (proven co-resident R5).
#define CBLOCKS 256
#define C_NPW   ((NPL / CBLOCKS) / WPB)   // 8 nodes per wave per level

// Fallback (per-level normal launches) config.
#define FBLOCKS 1024
#define F_NPW   ((NPL / FBLOCKS) / WPB)   // 2 nodes per wave per level

// ---- coherent (write-through, L2-bypassing) accessors: sc0 sc1 ops go to
// the memory-side L3, which is coherent across XCDs. No buffer_wbl2/inv
// cache walks anywhere in this kernel.
__device__ __forceinline__ float co_ld(const float* p) {
    return __hip_atomic_load(p, __ATOMIC_RELAXED, __HIP_MEMORY_SCOPE_AGENT);
}
__device__ __forceinline__ void co_st(float* p, float v) {
    __hip_atomic_store(p, v, __ATOMIC_RELAXED, __HIP_MEMORY_SCOPE_AGENT);
}

__device__ __forceinline__ void load_wrow(float* dst, const float* W, int row) {
    const float4* p = (const float4*)(W + row * DIM);   // 256B-aligned row
    #pragma unroll
    for (int q = 0; q < DIM / 4; ++q) {
        float4 v = p[q];
        dst[4*q+0] = v.x; dst[4*q+1] = v.y;
        dst[4*q+2] = v.z; dst[4*q+3] = v.w;
    }
}

// Monotonic grid barrier: no resets, no sense reversal, no fences.
// __syncthreads() drains each wave's vmcnt before s_barrier, so all of this
// block's write-through stores are visible at L3 before the arrive.
__device__ __forceinline__ void gridbar(int* cnt, int target) {
    __syncthreads();
    if (threadIdx.x == 0) {
        __hip_atomic_fetch_add(cnt, 1, __ATOMIC_RELAXED,
                               __HIP_MEMORY_SCOPE_AGENT);
        while (__hip_atomic_load(cnt, __ATOMIC_RELAXED,
                                 __HIP_MEMORY_SCOPE_AGENT) < target)
            __builtin_amdgcn_s_sleep(8);
    }
    asm volatile("" ::: "memory");   // no load hoisting above the spin
    __syncthreads();
}

// Process `nnodes` consecutive nodes of level `lvl` on one wave.
// Wave = node (sequential); lane = output dim. Software pipeline: node c+1's
// gathers are issued (not summed) before node c's GEMV consumes its own.
template<bool COH>
__device__ __forceinline__ void run_level(
    const float* __restrict__ x, const int* __restrict__ eb,
    float* __restrict__ out,
    const float* wr, const float* wl, float bias,
    int lvl, int lane, int w, int pbase, int nnodes,
    float (*sX)[DIM], float (*sA)[DIM])
{
    const long gbase = (long)lvl * NPL;

    float xc, xn = 0.f;
    float gc[CPN], gn[CPN];

    xc = x[(gbase + pbase) * DIM + lane];
    if (lvl > 0) {
        const int* ep = eb + (long)pbase * CPN;
        #pragma unroll
        for (int j = 0; j < CPN; ++j) {
            const float* src = &out[(long)ep[j] * DIM + lane];
            gc[j] = COH ? co_ld(src) : *src;     // coalesced 256B per wave
        }
    }

    for (int c = 0; c < nnodes; ++c) {
        if (c + 1 < nnodes) {                    // issue next node's loads
            const int p1 = pbase + c + 1;
            xn = x[(gbase + p1) * DIM + lane];
            if (lvl > 0) {
                const int* ep = eb + (long)p1 * CPN;
                #pragma unroll
                for (int j = 0; j < CPN; ++j) {
                    const float* src = &out[(long)ep[j] * DIM + lane];
                    gn[j] = COH ? co_ld(src) : *src;
                }
            }
        }

        float agg = 0.0f;
        if (lvl > 0) {
            #pragma unroll
            for (int j = 0; j < CPN; ++j) agg += gc[j];
        }
        // Per-wave LDS broadcast slot (DS pipe in-order within a wave).
        sX[w][lane] = xc;
        sA[w][lane] = agg;

        // Dual GEMV, 4 interleaved accumulators.
        float a0 = 0.f, a1 = 0.f, a2 = 0.f, a3 = (lvl > 0) ? bias : 0.f;
        const float4* A = (const float4*)sX[w];  // broadcast: conflict-free
        const float4* B = (const float4*)sA[w];
        #pragma unroll
        for (int k = 0; k < DIM / 4; ++k) {
            float4 av = A[k], bv = B[k];
            a0 += av.x * wr[4*k+0];
            a1 += av.y * wr[4*k+1];
            a2 += av.z * wr[4*k+2];
            a3 += av.w * wr[4*k+3];
            a0 += bv.x * wl[4*k+0];
            a1 += bv.y * wl[4*k+1];
            a2 += bv.z * wl[4*k+2];
            a3 += bv.w * wl[4*k+3];
        }
        float r = (a0 + a1) + (a2 + a3);
        if (lvl > 0) r = tanhf(r);
        float* dst = &out[(gbase + pbase + c) * DIM + lane];
        if (COH) co_st(dst, r); else *dst = r;

        xc = xn;
        #pragma unroll
        for (int j = 0; j < CPN; ++j) gc[j] = gn[j];
    }
}

// ---------------- Fused cooperative kernel (1 dispatch) ----------------
__global__ __launch_bounds__(TPB, 2) void dag_fused(
    const float* __restrict__ x, const int* __restrict__ src,
    const float* __restrict__ Wl, const float* __restrict__ bl,
    const float* __restrict__ Wr, float* __restrict__ out,
    int* __restrict__ barcnt)
{
    __shared__ __align__(16) float sX[WPB][DIM];
    __shared__ __align__(16) float sA[WPB][DIM];

    const int lane = threadIdx.x & 63;
    const int w    = threadIdx.x >> 6;

    float wr[DIM], wl[DIM];
    load_wrow(wr, Wr, lane);
    load_wrow(wl, Wl, lane);
    const float bias = bl[lane];

    const int pbase = blockIdx.x * (NPL / CBLOCKS) + w * C_NPW;

    for (int lvl = 0; lvl < NLEV; ++lvl) {
        run_level<true>(x, src + (long)(lvl - 1) * EPL, out,
                        wr, wl, bias, lvl, lane, w, pbase, C_NPW, sX, sA);
        if (lvl + 1 < NLEV)
            gridbar(barcnt, (lvl + 1) * CBLOCKS);
    }
}

// ---------------- Fallback: one normal kernel per level ----------------
__global__ __launch_bounds__(TPB) void dag_level(
    const float* __restrict__ x, const int* __restrict__ src,
    const float* __restrict__ Wl, const float* __restrict__ bl,
    const float* __restrict__ Wr, float* __restrict__ out, int lvl)
{
    __shared__ __align__(16) float sX[WPB][DIM];
    __shared__ __align__(16) float sA[WPB][DIM];

    const int lane = threadIdx.x & 63;
    const int w    = threadIdx.x >> 6;

    float wr[DIM], wl[DIM];
    load_wrow(wr, Wr, lane);
    load_wrow(wl, Wl, lane);
    const float bias = bl[lane];

    const int pbase = blockIdx.x * (NPL / FBLOCKS) + w * F_NPW;
    run_level<false>(x, src + (long)(lvl - 1) * EPL, out,
                     wr, wl, bias, lvl, lane, w, pbase, F_NPW, sX, sA);
}

extern "C" void kernel_launch(void* const* d_in, const int* in_sizes, int n_in,
                              void* d_out, int out_size, void* d_ws, size_t ws_size,
                              hipStream_t stream) {
    const float* x  = (const float*)d_in[0];   // [131072,64] f32
    const int*   ei = (const int*)d_in[1];     // [2, 917504] int32
    const float* Wl = (const float*)d_in[2];   // [64,64] f32
    const float* bl = (const float*)d_in[3];   // [64]    f32
    const float* Wr = (const float*)d_in[4];   // [64,64] f32
    float* out = (float*)d_out;                // [131072,64] f32
    int* barcnt = (int*)d_ws;                  // barrier counter (monotonic)

    const int* src = ei;                       // first E entries = src row

    // d_ws is poisoned 0xAA before every timed launch: zero the counter
    // inside the captured work (async memset on stream is graph-legal).
    hipMemsetAsync(barcnt, 0, 64, stream);

    void* args[] = {(void*)&x, (void*)&src, (void*)&Wl, (void*)&bl,
                    (void*)&Wr, (void*)&out, (void*)&barcnt};
    hipError_t e = hipLaunchCooperativeKernel((const void*)dag_fused,
                                              dim3(CBLOCKS), dim3(TPB),
                                              args, 0, stream);
    if (e != hipSuccess) {
        (void)hipGetLastError();               // clear sticky error
        // Proven-correct fallback: 8 dependent per-level launches
        // (kernel-boundary coherence, no fences needed).
        for (int lvl = 0; lvl < NLEV; ++lvl) {
            hipLaunchKernelGGL(dag_level, dim3(FBLOCKS), dim3(TPB), 0, stream,
                               x, src, Wl, bl, Wr, out, lvl);
        }
    }
}

// Round 7
// 226.120 us; speedup vs baseline: 4.3391x; 1.1835x over previous
//
#include <hip/hip_runtime.h>

// Problem constants (fixed instance): all float tensors are float32 on device.
#define NPL   16384        // nodes per level
#define DIM   64
#define CPN   8            // children per node
#define EPL   (NPL * CPN)  // edges per level block = 131072
#define NLEV  8

#define TPB     512
#define WPB     (TPB / 64) // 8 waves per block
#define CBLOCKS 256        // 1 block/CU (proven co-resident R4-R6)
#define NPB     (NPL / CBLOCKS)   // 64 nodes per block per level
#define NPW     (NPB / WPB)       // 8 nodes per wave per level

// ---- coherent (write-through, L2-bypassing) accessors: sc0 sc1 ops hit the
// memory-side coherent path. No cache-maintenance instructions anywhere.
__device__ __forceinline__ float co_ld(const float* p) {
    return __hip_atomic_load(p, __ATOMIC_RELAXED, __HIP_MEMORY_SCOPE_AGENT);
}
__device__ __forceinline__ void co_st(float* p, float v) {
    __hip_atomic_store(p, v, __ATOMIC_RELAXED, __HIP_MEMORY_SCOPE_AGENT);
}

__device__ __forceinline__ void load_wrow(float* dst, const float* W, int row) {
    const float4* p = (const float4*)(W + row * DIM);
    #pragma unroll
    for (int q = 0; q < DIM / 4; ++q) {
        float4 v = p[q];
        dst[4*q+0] = v.x; dst[4*q+1] = v.y;
        dst[4*q+2] = v.z; dst[4*q+3] = v.w;
    }
}

// tanh via hardware exp + rcp (~8 instrs vs ~40 for libm tanhf).
// |err| ~1e-6 abs, far under the 5.9e-2 threshold. Clamp avoids exp overflow.
__device__ __forceinline__ float fast_tanh(float z) {
    z = fminf(15.f, fmaxf(-15.f, z));
    float e = __expf(-2.f * z);
    return (1.f - e) * __builtin_amdgcn_rcpf(1.f + e);
}

// Monotonic grid barrier (R6, proven): no fences, no cache walks.
__device__ __forceinline__ void gridbar(int* cnt, int target) {
    __syncthreads();
    if (threadIdx.x == 0) {
        __hip_atomic_fetch_add(cnt, 1, __ATOMIC_RELAXED,
                               __HIP_MEMORY_SCOPE_AGENT);
        while (__hip_atomic_load(cnt, __ATOMIC_RELAXED,
                                 __HIP_MEMORY_SCOPE_AGENT) < target)
            __builtin_amdgcn_s_sleep(8);
    }
    asm volatile("" ::: "memory");
    __syncthreads();
}

// ---------------- Phase A: XR = x @ Wr^T for ALL 131072 rows ----------------
// Barrier-free, fully parallel. One dwordx4/lane fetches 4 rows per wave
// (lane>>4 = row-in-group, (lane&15)*4 = dim offset), pipelined 2 groups deep.
// Level-0 rows go straight to out (they ARE the final level-0 values, gathered
// cross-block later -> write-through). Levels 1-7 go to XR in d_ws, produced
// and consumed by the SAME wave -> normal cached ops.
template<bool COH>
__device__ __forceinline__ void phaseA(
    const float* __restrict__ x, const float* __restrict__ Wr,
    float* __restrict__ out, float* __restrict__ XR,
    int lane, int w, int blk, float* sX4 /* per-wave 256 floats */)
{
    float wr[DIM];
    load_wrow(wr, Wr, lane);

    const int base = blk * NPB + w * NPW;     // this wave's 8 nodes per level
    const int sub  = lane >> 4;               // row within 4-row group
    const int col4 = (lane & 15) * 4;         // dim offset of this lane's float4

    // 16 groups: group g covers rows L*NPL + base + (g&1)*4 + {0..3}, L = g>>1.
    float4 q0, q1, q2;
    #define ROWB(g) ((long)((g) >> 1) * NPL + base + ((g) & 1) * 4)
    q0 = *(const float4*)&x[(ROWB(0) + sub) * DIM + col4];
    q1 = *(const float4*)&x[(ROWB(1) + sub) * DIM + col4];

    for (int g = 0; g < 16; ++g) {
        if (g + 2 < 16)
            q2 = *(const float4*)&x[(ROWB(g + 2) + sub) * DIM + col4];

        *(float4*)&sX4[sub * DIM + col4] = q0;   // stage 4 rows in LDS

        const long rb = ROWB(g);
        const int  L  = g >> 1;
        #pragma unroll
        for (int rr = 0; rr < 4; ++rr) {
            float a0 = 0.f, a1 = 0.f, a2 = 0.f, a3 = 0.f;
            const float4* A = (const float4*)&sX4[rr * DIM];  // broadcast
            #pragma unroll
            for (int k = 0; k < DIM / 4; ++k) {
                float4 av = A[k];
                a0 += av.x * wr[4*k+0];
                a1 += av.y * wr[4*k+1];
                a2 += av.z * wr[4*k+2];
                a3 += av.w * wr[4*k+3];
            }
            float r = (a0 + a1) + (a2 + a3);
            const long gg = rb + rr;
            if (L == 0) {
                float* d = &out[gg * DIM + lane];
                if (COH) co_st(d, r); else *d = r;
            } else {
                XR[gg * DIM + lane] = r;          // same-wave consumer: cached
            }
        }
        q0 = q1; q1 = q2;
    }
    #undef ROWB
}

// ---------------- Phase B: one level, out = tanh(XR + agg·Wl^T + b) --------
// Wave = node (sequential). All 64 child indices for the wave's 8 nodes are
// loaded in ONE coalesced load (one per lane), then broadcast per-gather via
// v_readlane -> SGPR base addressing. Gathers + XR loads pipelined 2 nodes
// deep (issued, not summed) so L3 latency hides under ~2 nodes of compute.
template<bool COH>
__device__ __forceinline__ void phaseB(
    const int* __restrict__ eb,          // src + (L-1)*EPL
    const float* __restrict__ XR, float* __restrict__ out,
    const float* wl, float bias,
    int L, int lane, int w, int blk, float* sA /* per-wave 64 floats */)
{
    const int  pbase = blk * NPB + w * NPW;
    const long gbase = (long)L * NPL;

    // lane l holds child index of node (pbase + l/8), slot (l%8)
    const int vidx = eb[pbase * CPN + lane];

    float g0[CPN], g1[CPN], g2[CPN];
    float xr0, xr1, xr2;

    #define ISSUE(c, gg, xr)                                                  \
        {                                                                     \
            _Pragma("unroll")                                                 \
            for (int j = 0; j < CPN; ++j) {                                   \
                int s = __builtin_amdgcn_readlane(vidx, (c) * CPN + j);       \
                const float* p = &out[(long)s * DIM + lane];                  \
                gg[j] = COH ? co_ld(p) : *p;                                  \
            }                                                                 \
            xr = XR[(gbase + pbase + (c)) * DIM + lane];                      \
        }

    ISSUE(0, g0, xr0);
    ISSUE(1, g1, xr1);

    #pragma unroll
    for (int c = 0; c < NPW; ++c) {
        if (c + 2 < NPW) ISSUE(c + 2, g2, xr2);

        float agg = 0.f;
        #pragma unroll
        for (int j = 0; j < CPN; ++j) agg += g0[j];
        sA[lane] = agg;                            // per-wave slot, in-order DS

        float a0 = 0.f, a1 = 0.f, a2 = 0.f, a3 = bias + xr0;
        const float4* B = (const float4*)sA;       // broadcast: conflict-free
        #pragma unroll
        for (int k = 0; k < DIM / 4; ++k) {
            float4 bv = B[k];
            a0 += bv.x * wl[4*k+0];
            a1 += bv.y * wl[4*k+1];
            a2 += bv.z * wl[4*k+2];
            a3 += bv.w * wl[4*k+3];
        }
        float r = fast_tanh((a0 + a1) + (a2 + a3));
        float* d = &out[(gbase + pbase + c) * DIM + lane];
        if (COH) co_st(d, r); else *d = r;

        #pragma unroll
        for (int j = 0; j < CPN; ++j) { g0[j] = g1[j]; g1[j] = g2[j]; }
        xr0 = xr1; xr1 = xr2;
    }
    #undef ISSUE
}

// ---------------- Fused cooperative kernel (1 dispatch) ----------------
__global__ __launch_bounds__(TPB, 2) void dag_fused(
    const float* __restrict__ x, const int* __restrict__ src,
    const float* __restrict__ Wl, const float* __restrict__ bl,
    const float* __restrict__ Wr, float* __restrict__ out,
    float* __restrict__ ws)
{
    __shared__ __align__(16) float sbuf[WPB][256];   // 8 KB: phase A 4-row stage

    const int lane = threadIdx.x & 63;
    const int w    = threadIdx.x >> 6;

    int*   barcnt = (int*)ws;
    float* XR     = ws + 64;       // 256 B offset, 33.5 MB region

    phaseA<true>(x, Wr, out, XR, lane, w, blockIdx.x, sbuf[w]);
    gridbar(barcnt, CBLOCKS);

    float wl[DIM];
    load_wrow(wl, Wl, lane);
    const float bias = bl[lane];

    for (int L = 1; L < NLEV; ++L) {
        phaseB<true>(src + (long)(L - 1) * EPL, XR, out, wl, bias,
                     L, lane, w, blockIdx.x, sbuf[w]);
        if (L + 1 < NLEV)
            gridbar(barcnt, (L + 1) * CBLOCKS);
    }
}

// ---------------- Fallback: normal launches (kernel-boundary coherence) ----
__global__ __launch_bounds__(TPB) void dag_phaseA_k(
    const float* __restrict__ x, const float* __restrict__ Wr,
    float* __restrict__ out, float* __restrict__ ws)
{
    __shared__ __align__(16) float sbuf[WPB][256];
    const int lane = threadIdx.x & 63;
    const int w    = threadIdx.x >> 6;
    phaseA<false>(x, Wr, out, ws + 64, lane, w, blockIdx.x, sbuf[w]);
}

__global__ __launch_bounds__(TPB) void dag_phaseB_k(
    const int* __restrict__ src, const float* __restrict__ Wl,
    const float* __restrict__ bl, float* __restrict__ out,
    float* __restrict__ ws, int L)
{
    __shared__ __align__(16) float sbuf[WPB][256];
    const int lane = threadIdx.x & 63;
    const int w    = threadIdx.x >> 6;
    float wl[DIM];
    load_wrow(wl, Wl, lane);
    phaseB<false>(src + (long)(L - 1) * EPL, ws + 64, out, wl, bl[lane],
                  L, lane, w, blockIdx.x, sbuf[w]);
}

extern "C" void kernel_launch(void* const* d_in, const int* in_sizes, int n_in,
                              void* d_out, int out_size, void* d_ws, size_t ws_size,
                              hipStream_t stream) {
    const float* x  = (const float*)d_in[0];   // [131072,64] f32
    const int*   ei = (const int*)d_in[1];     // [2, 917504] int32
    const float* Wl = (const float*)d_in[2];   // [64,64] f32
    const float* bl = (const float*)d_in[3];   // [64]    f32
    const float* Wr = (const float*)d_in[4];   // [64,64] f32
    float* out = (float*)d_out;                // [131072,64] f32
    float* ws  = (float*)d_ws;                 // [0..63]=barrier, [64..]=XR

    const int* src = ei;                       // first E entries = src row

    // Zero the barrier counter inside the captured work (d_ws is re-poisoned
    // 0xAA before every timed launch). XR needs no init (fully overwritten).
    hipMemsetAsync(ws, 0, 256, stream);

    void* args[] = {(void*)&x, (void*)&src, (void*)&Wl, (void*)&bl,
                    (void*)&Wr, (void*)&out, (void*)&ws};
    hipError_t e = hipLaunchCooperativeKernel((const void*)dag_fused,
                                              dim3(CBLOCKS), dim3(TPB),
                                              args, 0, stream);
    if (e != hipSuccess) {
        (void)hipGetLastError();               // clear sticky error
        hipLaunchKernelGGL(dag_phaseA_k, dim3(CBLOCKS), dim3(TPB), 0, stream,
                           x, Wr, out, ws);
        for (int L = 1; L < NLEV; ++L) {
            hipLaunchKernelGGL(dag_phaseB_k, dim3(CBLOCKS), dim3(TPB), 0, stream,
                               src, Wl, bl, out, ws, L);
        }
    }
}